// Round 10
// baseline (2345.913 us; speedup 1.0000x reference)
//
#include <hip/hip_runtime.h>
#include <math.h>

#define NOUTK 1024
#define PHK   512
#define HID   24
#define G4    96
#define LSTEPS 32
#define BATCH 8192
#define EPB   16

// XOR swizzle: keeps 4-col groups contiguous (bits 0-1 untouched) while
// spreading the lane*8 stride across banks. Hand-check (col = lane*8, b128):
// every 16-lane quarter hits each of the 32 banks exactly twice -> free.
#define SW(c) ((c) ^ ((((c) >> 5) & 7) << 2))

// Dynamic LDS: 145,152 B (1 block/CU; >64KB dynamic proven by R6's 118.7KB).
// ZERO barriers in the main loop: one wave owns one element outright.
struct SmemD {
  float  stg[HID][NOUTK];    // w_lin both halves, col-swizzled          98304 B
  float  blinS[NOUTK];       // b_lin, same swizzle                       4096 B
  float  whhT[HID][G4];      // w_hh transposed [k][row]                  9216 B
  float  bihs[G4];           //                                            384 B
  float  bhhs[G4];           //                                            384 B
  double zbuf[4][NOUTK];     // pass-A logits/exps, per-lane-private     32768 B
};

__device__ __forceinline__ float bf2f(unsigned short v) {
  union { unsigned u; float f; } x; x.u = ((unsigned)v) << 16; return x.f;
}
__device__ __forceinline__ unsigned short f2bf(float f) {
  unsigned u = __float_as_uint(f);
  unsigned r = 0x7FFFu + ((u >> 16) & 1u);
  return (unsigned short)((u + r) >> 16);
}
__device__ __forceinline__ float bfsnap(float f) { return bf2f(f2bf(f)); }

// One-time w_ih transpose into d_ws: the one-hot gather reads 96 contiguous
// floats instead of 96 lines at 4 KB stride.
__global__ void transpose_wih(const float* __restrict__ wih, float* __restrict__ wT) {
  const int idx = blockIdx.x * 256 + threadIdx.x;    // 98304 total
  const int a = idx / G4, row = idx % G4;
  wT[idx] = wih[row * NOUTK + a];
}

__global__ void __launch_bounds__(1024)
policy_kernel(const float* __restrict__ wihf,  const float* __restrict__ whhf,
              const float* __restrict__ bihf,  const float* __restrict__ bhhf,
              const float* __restrict__ wlinf, const float* __restrict__ blinf,
              const float* __restrict__ uf,    float* __restrict__ outg,
              const float* __restrict__ wT) {
  extern __shared__ char smraw[];
  SmemD* sm = (SmemD*)smraw;
  const int tid  = threadIdx.x;
  const int wave = tid >> 6;                // wave w owns element w
  const int lane = tid & 63;
  const int geL  = blockIdx.x * EPB + wave;
  const int useT = (wT != nullptr);
  const int zo   = wave * 64 + lane;        // private zbuf slot

  // ---------------- one-time staging ----------------
  {
    const float4* row4 = (const float4*)(wlinf + tid * HID);  // w_lin row tid
    const int p = SW(tid);
    #pragma unroll
    for (int q = 0; q < 6; ++q) {
      const float4 v = row4[q];
      sm->stg[q * 4 + 0][p] = v.x; sm->stg[q * 4 + 1][p] = v.y;
      sm->stg[q * 4 + 2][p] = v.z; sm->stg[q * 4 + 3][p] = v.w;
    }
    sm->blinS[p] = blinf[tid];
  }
  for (int i = tid; i < G4 * HID; i += 1024)
    sm->whhT[i % HID][i / HID] = whhf[i];
  if (tid < G4) { sm->bihs[tid] = bihf[tid]; sm->bhhs[tid] = bhhf[tid]; }
  __syncthreads();                          // the ONLY barrier

  double creg = 0.0, hreg = 0.0;            // c,h: lanes 0..23 hold index lane
  int    areg = -1;                         // previous action (-1 = zeros)

  for (int t = 0; t < LSTEPS; ++t) {
    const int odd  = t & 1;
    const int base = odd ? PHK : 0;

    // -------- phase L: LSTM, intra-wave (lanes 0..47, 2 gate-rows each) ---
    // lanes 0..23: rows j, j+24 (i,f); lanes 24..47: rows 48+j, 72+j (g,o).
    // h_prev via shfl from lanes 0..23 -- no LDS, no ordering hazards.
    {
      double aA = 0.0, aB = 0.0;
      if (lane < 48) {
        const int rA = (lane < 24) ? lane : lane + 24;
        const int rB = rA + 24;
        double mvA = 0.0, mvB = 0.0;
        #pragma unroll
        for (int k = 0; k < HID; ++k) {
          const double hk = __shfl(hreg, k);
          mvA = fma(hk, (double)sm->whhT[k][rA], mvA);
          mvB = fma(hk, (double)sm->whhT[k][rB], mvB);
        }
        const double cA = (areg >= 0)
            ? (double)(useT ? wT[areg * G4 + rA] : wihf[rA * NOUTK + areg]) : 0.0;
        const double cB = (areg >= 0)
            ? (double)(useT ? wT[areg * G4 + rB] : wihf[rB * NOUTK + areg]) : 0.0;
        const double gA = ((cA + (double)sm->bihs[rA]) + mvA) + (double)sm->bhhs[rA];
        const double gB = ((cB + (double)sm->bihs[rB]) + mvB) + (double)sm->bhhs[rB];
        aA = (lane < 24) ? (1.0 / (1.0 + exp(-gA))) : tanh(gA);
        aB = 1.0 / (1.0 + exp(-gB));        // f and o are both sigmoid
      }
      const double gvx = __shfl(aA, lane + 24);   // g for lanes 0..23
      const double ogx = __shfl(aB, lane + 24);   // o for lanes 0..23
      if (lane < 24) {
        creg = aB * creg + aA * gvx;              // c = f*c + i*g
        hreg = ogx * tanh(creg);                  // h = o*tanh(c)
      }
    }

    // -------- phase G: 8 cols/lane (contiguous), two 4-col passes ---------
    const int cg0 = base + lane * 8;
    const int pA  = SW(cg0);
    const int pB  = SW(cg0 + 4);
    double za0 = 0.0, za1 = 0.0, za2 = 0.0, za3 = 0.0;
    #pragma unroll
    for (int k = 0; k < HID; ++k) {
      const double hk = __shfl(hreg, k);
      const float4 w = *(const float4*)&sm->stg[k][pA];
      za0 = fma(hk, (double)w.x, za0); za1 = fma(hk, (double)w.y, za1);
      za2 = fma(hk, (double)w.z, za2); za3 = fma(hk, (double)w.w, za3);
    }
    {
      const float4 b = *(const float4*)&sm->blinS[pA];
      za0 += (double)b.x; za1 += (double)b.y; za2 += (double)b.z; za3 += (double)b.w;
    }
    double pm = fmax(fmax(za0, za1), fmax(za2, za3));
    sm->zbuf[0][zo] = za0; sm->zbuf[1][zo] = za1;   // park pass-A logits
    sm->zbuf[2][zo] = za2; sm->zbuf[3][zo] = za3;   // (private slot)
    // pass B reuses za registers
    za0 = 0.0; za1 = 0.0; za2 = 0.0; za3 = 0.0;
    #pragma unroll
    for (int k = 0; k < HID; ++k) {
      const double hk = __shfl(hreg, k);
      const float4 w = *(const float4*)&sm->stg[k][pB];
      za0 = fma(hk, (double)w.x, za0); za1 = fma(hk, (double)w.y, za1);
      za2 = fma(hk, (double)w.z, za2); za3 = fma(hk, (double)w.w, za3);
    }
    {
      const float4 b = *(const float4*)&sm->blinS[pB];
      za0 += (double)b.x; za1 += (double)b.y; za2 += (double)b.z; za3 += (double)b.w;
    }
    pm = fmax(pm, fmax(fmax(za0, za1), fmax(za2, za3)));

    // -------- max butterfly (exact) --------
    #pragma unroll
    for (int d = 1; d < 64; d <<= 1) pm = fmax(pm, __shfl_xor(pm, d));
    const double Me = pm;

    // -------- exp + lane-sum + sum butterfly --------
    double ps;
    {
      double e0 = exp(sm->zbuf[0][zo] - Me); sm->zbuf[0][zo] = e0;
      double e1 = exp(sm->zbuf[1][zo] - Me); sm->zbuf[1][zo] = e1;
      double e2 = exp(sm->zbuf[2][zo] - Me); sm->zbuf[2][zo] = e2;
      double e3 = exp(sm->zbuf[3][zo] - Me); sm->zbuf[3][zo] = e3;
      za0 = exp(za0 - Me); za1 = exp(za1 - Me);
      za2 = exp(za2 - Me); za3 = exp(za3 - Me);
      ps = ((((((e0 + e1) + e2) + e3) + za0) + za1) + za2) + za3;
    }
    double S = ps;
    #pragma unroll
    for (int d = 1; d < 64; d <<= 1) S += __shfl_xor(S, d);
    const double inv = 1.0 / S;

    // -------- lane totals scan (Kogge-Stone) --------
    const double tt = ps * inv;
    double incl = tt;
    #pragma unroll
    for (int d = 1; d < 64; d <<= 1) {
      const double o = __shfl_up(incl, d);
      if (lane >= d) incl += o;
    }
    const double exb = incl - tt;           // exclusive prefix for this lane

    // -------- crossing search (sequential col order) --------
    const double ue = (double)uf[t * BATCH + geL];
    double pr = exb, rsel = 0.0, rr0v = 0.0;
    int jloc = 0x7FFFFFFF;
#define CROSSR(R, EV)                                                        \
    { const double rr = (EV) * inv;                                          \
      if ((R) == 0) rr0v = rr;                                               \
      pr += rr;                                                              \
      if (jloc == 0x7FFFFFFF && pr > ue) { jloc = lane * 8 + (R); rsel = rr; } }
    CROSSR(0, sm->zbuf[0][zo])
    CROSSR(1, sm->zbuf[1][zo])
    CROSSR(2, sm->zbuf[2][zo])
    CROSSR(3, sm->zbuf[3][zo])
    CROSSR(4, za0) CROSSR(5, za1) CROSSR(6, za2) CROSSR(7, za3)
#undef CROSSR
    #pragma unroll
    for (int d = 1; d < 64; d <<= 1) {
      const int    oj = __shfl_xor(jloc, d);
      const double orr = __shfl_xor(rsel, d);
      if (oj < jloc) { jloc = oj; rsel = orr; }
    }
    const double r0 = __shfl(rr0v, 0);      // prob of active col 0

    // -------- decide + emit (all lanes agree; lane 0 writes) --------
    double p;
    if (jloc == 0x7FFFFFFF) {               // cumsum never exceeded u:
      areg = 0;                             // np.argmax(all False) == 0
      p = odd ? 0.0 : r0;                   // out[0] (masked -> 0 on odd)
    } else {
      areg = base + jloc; p = rsel;
    }
    if (lane == 0) {
      const int io = geL * LSTEPS + t;
      outg[io]                  = bfsnap((float)p);
      outg[BATCH * LSTEPS + io] = bfsnap((float)areg);
    }
  }
}

extern "C" void kernel_launch(void* const* d_in, const int* in_sizes, int n_in,
                              void* d_out, int out_size, void* d_ws, size_t ws_size,
                              hipStream_t stream) {
  (void)in_sizes; (void)n_in; (void)out_size;
  const float* wihf = (const float*)d_in[0];
  float* wT = nullptr;
  if (ws_size >= (size_t)(G4 * NOUTK * 4)) {
    wT = (float*)d_ws;
    transpose_wih<<<G4 * NOUTK / 256, 256, 0, stream>>>(wihf, wT);
  }
  hipFuncSetAttribute((const void*)policy_kernel,
                      hipFuncAttributeMaxDynamicSharedMemorySize,
                      (int)sizeof(SmemD));
  policy_kernel<<<BATCH / EPB, 1024, sizeof(SmemD), stream>>>(
      wihf, (const float*)d_in[1], (const float*)d_in[2],
      (const float*)d_in[3], (const float*)d_in[4], (const float*)d_in[5],
      (const float*)d_in[6], (float*)d_out, wT);
}

// Round 11
// 2152.806 us; speedup vs baseline: 1.0897x; 1.0897x over previous
//
#include <hip/hip_runtime.h>
#include <math.h>

#define NOUTK 1024
#define PHK   512
#define HID   24
#define G4    96
#define LSTEPS 32
#define BATCH 8192
#define EPB   16
#define CW    9     // chunk width: 8 cols + 1 pad word

// Dynamic LDS: 125,184 B, 1 block/CU, 16 waves. ZERO LDS writes in the main
// loop; zero barriers in the main loop (one wave owns one element).
// Bank math for stg reads (the R10 killer, 3.3e8 conflicts): word index =
// k*1152 + (c0+lane)*9 + j, 1152%32==0, gcd(9,32)==1 -> for each word-phase j
// the 64 lanes cover all 32 banks exactly twice -> 2-way = free.
struct SmemD {
  float stg[HID][128 * CW];  // w_lin both halves, chunk-padded        110592 B
  float whhT[HID][G4];       // w_hh transposed [k][row]                 9216 B
  float blinS[128 * CW];     // b_lin, same chunk padding                4608 B
  float bihs[G4], bhhs[G4];  //                                           768 B
};

__device__ __forceinline__ float bf2f(unsigned short v) {
  union { unsigned u; float f; } x; x.u = ((unsigned)v) << 16; return x.f;
}
__device__ __forceinline__ unsigned short f2bf(float f) {
  unsigned u = __float_as_uint(f);
  unsigned r = 0x7FFFu + ((u >> 16) & 1u);
  return (unsigned short)((u + r) >> 16);
}
__device__ __forceinline__ float bfsnap(float f) { return bf2f(f2bf(f)); }

// Branch-free f64 exp: n = rint(x*log2e); r = x - n*ln2 (hi/lo split);
// Taylor-11 on |r|<=0.347 (trunc err ~6e-15 rel); scale by 2^n via exponent
// bits. Replaces ocml exp/tanh (table/branch/temp-heavy -- suspected source
// of the chronic 64-VGPR scratch signature in R6-R10).
__device__ __forceinline__ double fexp(double x) {
  const double fn = __builtin_rint(x * 1.4426950408889634074);
  const int n = (int)fn;
  double r = __builtin_fma(-fn, 6.93147180369123816490e-01, x);
  r = __builtin_fma(-fn, 1.90821492927058770002e-10, r);
  double p = 2.5052108385441718775e-08;                  // 1/11!
  p = __builtin_fma(p, r, 2.7557319223985890653e-07);    // 1/10!
  p = __builtin_fma(p, r, 2.7557319223985892511e-06);    // 1/9!
  p = __builtin_fma(p, r, 2.4801587301587301587e-05);    // 1/8!
  p = __builtin_fma(p, r, 1.9841269841269841270e-04);    // 1/7!
  p = __builtin_fma(p, r, 1.3888888888888888889e-03);    // 1/6!
  p = __builtin_fma(p, r, 8.3333333333333333333e-03);    // 1/5!
  p = __builtin_fma(p, r, 4.1666666666666666667e-02);    // 1/4!
  p = __builtin_fma(p, r, 1.6666666666666666667e-01);    // 1/3!
  p = __builtin_fma(p, r, 0.5);
  p = __builtin_fma(p, r, 1.0);
  p = __builtin_fma(p, r, 1.0);
  return p * __longlong_as_double(((long long)(n + 1023)) << 52);
}
__device__ __forceinline__ double sigd(double x) { return 1.0 / (1.0 + fexp(-x)); }
__device__ __forceinline__ double tanhd(double x) {
  const double e2 = fexp(2.0 * x);
  return (e2 - 1.0) / (e2 + 1.0);
}

// One-time w_ih transpose into d_ws: the one-hot gather reads 96 contiguous
// floats (2 lines) instead of 96 lines at 4 KB stride.
__global__ void transpose_wih(const float* __restrict__ wih, float* __restrict__ wT) {
  const int idx = blockIdx.x * 256 + threadIdx.x;    // 98304 total
  const int a = idx / G4, row = idx % G4;
  wT[idx] = wih[row * NOUTK + a];
}

__global__ void __launch_bounds__(1024)
policy_kernel(const float* __restrict__ wihf,  const float* __restrict__ whhf,
              const float* __restrict__ bihf,  const float* __restrict__ bhhf,
              const float* __restrict__ wlinf, const float* __restrict__ blinf,
              const float* __restrict__ uf,    float* __restrict__ outg,
              const float* __restrict__ wT) {
  extern __shared__ char smraw[];
  SmemD* sm = (SmemD*)smraw;
  const int tid  = threadIdx.x;
  const int wave = tid >> 6;                // wave w owns element w
  const int lane = tid & 63;
  const int geL  = blockIdx.x * EPB + wave;
  const int useT = (wT != nullptr);

  // ---------------- one-time staging ----------------
  {
    const float4* row4 = (const float4*)(wlinf + tid * HID);  // w_lin row tid
    const int p = (tid >> 3) * CW + (tid & 7);
    #pragma unroll
    for (int q = 0; q < 6; ++q) {
      const float4 v = row4[q];
      sm->stg[q * 4 + 0][p] = v.x; sm->stg[q * 4 + 1][p] = v.y;
      sm->stg[q * 4 + 2][p] = v.z; sm->stg[q * 4 + 3][p] = v.w;
    }
    sm->blinS[p] = blinf[tid];
  }
  for (int i = tid; i < G4 * HID; i += 1024)
    sm->whhT[i % HID][i / HID] = whhf[i];
  if (tid < G4) { sm->bihs[tid] = bihf[tid]; sm->bhhs[tid] = bhhf[tid]; }
  __syncthreads();                          // the ONLY barrier

  double creg = 0.0, hreg = 0.0;            // c,h: lanes 0..23 hold index lane
  int    areg = -1;                         // previous action (-1 = zeros)

  for (int t = 0; t < LSTEPS; ++t) {
    const int odd  = t & 1;
    const int base = odd ? PHK : 0;
    const double ue = (double)uf[t * BATCH + geL];   // broadcast load

    // -------- phase L: LSTM, intra-wave (lanes 0..47, 2 gate-rows each) ---
    {
      double aA = 0.0, aB = 0.0;
      if (lane < 48) {
        const int rA = (lane < 24) ? lane : lane + 24;   // rows i/g
        const int rB = rA + 24;                          // rows f/o
        double mvA = 0.0, mvB = 0.0;
        #pragma unroll
        for (int k = 0; k < HID; ++k) {
          const double hk = __shfl(hreg, k);
          mvA = __builtin_fma(hk, (double)sm->whhT[k][rA], mvA);
          mvB = __builtin_fma(hk, (double)sm->whhT[k][rB], mvB);
        }
        const double cA = (areg >= 0)
            ? (double)(useT ? wT[areg * G4 + rA] : wihf[rA * NOUTK + areg]) : 0.0;
        const double cB = (areg >= 0)
            ? (double)(useT ? wT[areg * G4 + rB] : wihf[rB * NOUTK + areg]) : 0.0;
        const double gA = ((cA + (double)sm->bihs[rA]) + mvA) + (double)sm->bhhs[rA];
        const double gB = ((cB + (double)sm->bihs[rB]) + mvB) + (double)sm->bhhs[rB];
        aA = (lane < 24) ? sigd(gA) : tanhd(gA);
        aB = sigd(gB);                       // f and o are both sigmoid
      }
      const double gvx = __shfl(aA, lane + 24);   // g for lanes 0..23
      const double ogx = __shfl(aB, lane + 24);   // o for lanes 0..23
      if (lane < 24) {
        creg = aB * creg + aA * gvx;              // c = f*c + i*g
        hreg = ogx * tanhd(creg);                 // h = o*tanh(c)
      }
    }

    // -------- phase G: 8 contiguous cols/lane, conflict-free b32 reads ----
    const int ch = ((base >> 3) + lane) * CW;
    double z0 = 0.0, z1 = 0.0, z2 = 0.0, z3 = 0.0,
           z4 = 0.0, z5 = 0.0, z6 = 0.0, z7 = 0.0;
    #pragma unroll
    for (int k = 0; k < HID; ++k) {
      const double hk = __shfl(hreg, k);
      const float* wk = &sm->stg[k][ch];
      z0 = __builtin_fma(hk, (double)wk[0], z0);
      z1 = __builtin_fma(hk, (double)wk[1], z1);
      z2 = __builtin_fma(hk, (double)wk[2], z2);
      z3 = __builtin_fma(hk, (double)wk[3], z3);
      z4 = __builtin_fma(hk, (double)wk[4], z4);
      z5 = __builtin_fma(hk, (double)wk[5], z5);
      z6 = __builtin_fma(hk, (double)wk[6], z6);
      z7 = __builtin_fma(hk, (double)wk[7], z7);
    }
    {
      const float* bp = &sm->blinS[ch];
      z0 += (double)bp[0]; z1 += (double)bp[1]; z2 += (double)bp[2]; z3 += (double)bp[3];
      z4 += (double)bp[4]; z5 += (double)bp[5]; z6 += (double)bp[6]; z7 += (double)bp[7];
    }

    // -------- max butterfly (exact) --------
    double pm = fmax(fmax(fmax(z0, z1), fmax(z2, z3)),
                     fmax(fmax(z4, z5), fmax(z6, z7)));
    #pragma unroll
    for (int d = 1; d < 64; d <<= 1) pm = fmax(pm, __shfl_xor(pm, d));
    const double Me = pm;

    // -------- exp (in place) + lane sum + butterfly --------
    z0 = fexp(z0 - Me); z1 = fexp(z1 - Me); z2 = fexp(z2 - Me); z3 = fexp(z3 - Me);
    z4 = fexp(z4 - Me); z5 = fexp(z5 - Me); z6 = fexp(z6 - Me); z7 = fexp(z7 - Me);
    const double ps = ((((((z0 + z1) + z2) + z3) + z4) + z5) + z6) + z7;
    double S = ps;
    #pragma unroll
    for (int d = 1; d < 64; d <<= 1) S += __shfl_xor(S, d);
    const double inv = 1.0 / S;

    // -------- lane-total Kogge-Stone scan --------
    const double tt = ps * inv;
    double incl = tt;
    #pragma unroll
    for (int d = 1; d < 64; d <<= 1) {
      const double o = __shfl_up(incl, d);
      if (lane >= d) incl += o;
    }
    const double exb = incl - tt;           // exclusive prefix for this lane

    // -------- crossing search (sequential col order) --------
    double pr = exb, rsel = 0.0, rr0v = 0.0;
    int jloc = 0x7FFFFFFF;
#define CROSSR(R, EV)                                                        \
    { const double rr = (EV) * inv;                                          \
      if ((R) == 0) rr0v = rr;                                               \
      pr += rr;                                                              \
      if (jloc == 0x7FFFFFFF && pr > ue) { jloc = lane * 8 + (R); rsel = rr; } }
    CROSSR(0, z0) CROSSR(1, z1) CROSSR(2, z2) CROSSR(3, z3)
    CROSSR(4, z4) CROSSR(5, z5) CROSSR(6, z6) CROSSR(7, z7)
#undef CROSSR
    #pragma unroll
    for (int d = 1; d < 64; d <<= 1) {
      const int    oj  = __shfl_xor(jloc, d);
      const double orr = __shfl_xor(rsel, d);
      if (oj < jloc) { jloc = oj; rsel = orr; }
    }
    const double r0 = __shfl(rr0v, 0);      // prob of active col 0

    // -------- decide + emit (all lanes agree; lane 0 writes) --------
    double p;
    if (jloc == 0x7FFFFFFF) {               // cumsum never exceeded u:
      areg = 0;                             // np.argmax(all False) == 0
      p = odd ? 0.0 : r0;                   // out[0] (masked -> 0 on odd)
    } else {
      areg = base + jloc; p = rsel;
    }
    if (lane == 0) {
      const int io = geL * LSTEPS + t;
      outg[io]                  = bfsnap((float)p);
      outg[BATCH * LSTEPS + io] = bfsnap((float)areg);
    }
  }
}

extern "C" void kernel_launch(void* const* d_in, const int* in_sizes, int n_in,
                              void* d_out, int out_size, void* d_ws, size_t ws_size,
                              hipStream_t stream) {
  (void)in_sizes; (void)n_in; (void)out_size;
  const float* wihf = (const float*)d_in[0];
  float* wT = nullptr;
  if (ws_size >= (size_t)(G4 * NOUTK * 4)) {
    wT = (float*)d_ws;
    transpose_wih<<<G4 * NOUTK / 256, 256, 0, stream>>>(wihf, wT);
  }
  hipFuncSetAttribute((const void*)policy_kernel,
                      hipFuncAttributeMaxDynamicSharedMemorySize,
                      (int)sizeof(SmemD));
  policy_kernel<<<BATCH / EPB, 1024, sizeof(SmemD), stream>>>(
      wihf, (const float*)d_in[1], (const float*)d_in[2],
      (const float*)d_in[3], (const float*)d_in[4], (const float*)d_in[5],
      (const float*)d_in[6], (float*)d_out, wT);
}